// Round 15
// baseline (667.022 us; speedup 1.0000x reference)
//
#include <hip/hip_runtime.h>

#define D 128

typedef __attribute__((ext_vector_type(2))) float f32x2;
typedef __attribute__((ext_vector_type(4))) float f32x4;
typedef __attribute__((ext_vector_type(16))) float f32x16;
typedef __attribute__((ext_vector_type(2))) __fp16 fp16v2;
typedef __attribute__((ext_vector_type(4))) unsigned int u32x4;

// split f32 pair -> packed f16 hi-pair + lo-pair
__device__ __forceinline__ void split2(float a, float b, unsigned &hi, unsigned &lo) {
  fp16v2 h = __builtin_amdgcn_cvt_pkrtz(a, b);
  float ra = a - (float)h[0];
  float rb = b - (float)h[1];
  fp16v2 lv = __builtin_amdgcn_cvt_pkrtz(ra, rb);
  hi = __builtin_bit_cast(unsigned, h);
  lo = __builtin_bit_cast(unsigned, lv);
}

// Inline-asm MFMA, AGPR-forced, NON-volatile (R14): data deps via "+a" keep
// per-acc ordering; the scheduler may interleave VALU/LDS with MFMAs (R13's
// volatile blocks serialized the pipes: MfmaUtil+VALUBusy ~ 87%, ~80 cyc per
// MFMA from distance-1 dependent chains). Leading s_nop 1 covers the
// VALU-write -> MFMA-read hazard wherever the block lands (R13-proven).
__device__ __forceinline__ void mma_acc(f32x16 &c, u32x4 a, u32x4 b) {
  asm("s_nop 1\n\tv_mfma_f32_32x32x16_f16 %0, %1, %2, %0"
      : "+a"(c) : "v"(a), "v"(b));
}
__device__ __forceinline__ void mma_init(f32x16 &d, u32x4 a, u32x4 b,
                                         const f32x16 &cin) {
  asm("s_nop 1\n\tv_mfma_f32_32x32x16_f16 %0, %1, %2, %3"
      : "=&a"(d) : "v"(a), "v"(b), "a"(cin));
}
// Dependency-carrying MFMA->VALU fence: 24 wait states ordered AFTER the
// last MFMA writing any acc (input dep) and BEFORE any read (output dep).
// Survives scheduling without volatile.
__device__ __forceinline__ void accs_fence(f32x16 &a0, f32x16 &a1, f32x16 &a2,
                                           f32x16 &a3, f32x16 &a4, f32x16 &a5,
                                           f32x16 &a6, f32x16 &a7) {
  asm("s_nop 7\n\ts_nop 7\n\ts_nop 7"
      : "+a"(a0), "+a"(a1), "+a"(a2), "+a"(a3),
        "+a"(a4), "+a"(a5), "+a"(a6), "+a"(a7));
}

__device__ __forceinline__ f32x16 zero16() {
  f32x16 z;
#pragma unroll
  for (int e = 0; e < 16; ++e) z[e] = 0.f;
  return z;
}

// ---------------------------------------------------------------------------
// Kernel 1: W = 0.95 I - A^T A + B - B^T ;  Mm = 2 I - W
// ---------------------------------------------------------------------------
__global__ void wmat_kernel(const float* __restrict__ A, const float* __restrict__ B,
                            float* __restrict__ W, float* __restrict__ Mm) {
  const int i = blockIdx.x;
  const int j = threadIdx.x;
  float s = 0.f;
#pragma unroll 8
  for (int k = 0; k < D; ++k) s = fmaf(A[k * D + i], A[k * D + j], s);
  const float diag = (i == j) ? 1.f : 0.f;
  const float w = 0.95f * diag - s + B[i * D + j] - B[j * D + i];
  W[i * D + j] = w;
  Mm[i * D + j] = 2.f * diag - w;
}

// ---------------------------------------------------------------------------
// Kernel 2: Winv = Mm^{-1}, rank-4 block Gauss-Jordan, 32 barriers.
// ---------------------------------------------------------------------------
__global__ __launch_bounds__(1024) void inv_kernel(const float* __restrict__ Mm,
                                                   float* __restrict__ Winv) {
  __shared__ float PROW[2][4][256];
  __shared__ __align__(16) float PC[2][D][4];
  const int t = threadIdx.x;
  const int c = t & 255;
  const int rb = t >> 8;
  const int r0 = rb * 32;
  float aug[32];
#pragma unroll
  for (int rr = 0; rr < 32; ++rr) {
    const int r = r0 + rr;
    aug[rr] = (c < D) ? Mm[r * D + c] : ((c - D == r) ? 1.f : 0.f);
  }
  if (rb == 0) {
#pragma unroll
    for (int s = 0; s < 4; ++s) PROW[0][s][c] = aug[s];
  }
  if (c < 4) {
#pragma unroll
    for (int rr = 0; rr < 32; ++rr) PC[0][r0 + rr][c] = aug[rr];
  }
  __syncthreads();
#pragma unroll
  for (int p = 0; p < 32; ++p) {
    const int buf = p & 1;
    const int kp = 4 * p;
    float p4[4], Bk[4][4], Bi[4][4];
#pragma unroll
    for (int s = 0; s < 4; ++s) p4[s] = PROW[buf][s][c];
#pragma unroll
    for (int s = 0; s < 4; ++s)
#pragma unroll
      for (int j = 0; j < 4; ++j) {
        Bk[s][j] = PROW[buf][s][kp + j];
        Bi[s][j] = (s == j) ? 1.f : 0.f;
      }
#pragma unroll
    for (int k = 0; k < 4; ++k) {
      const float ip = 1.f / Bk[k][k];
#pragma unroll
      for (int j = 0; j < 4; ++j) { Bk[k][j] *= ip; Bi[k][j] *= ip; }
#pragma unroll
      for (int s = 0; s < 4; ++s)
        if (s != k) {
          const float f = Bk[s][k];
#pragma unroll
          for (int j = 0; j < 4; ++j) {
            Bk[s][j] = fmaf(-f, Bk[k][j], Bk[s][j]);
            Bi[s][j] = fmaf(-f, Bi[k][j], Bi[s][j]);
          }
        }
    }
    float y[4];
#pragma unroll
    for (int s = 0; s < 4; ++s)
      y[s] = fmaf(Bi[s][0], p4[0], fmaf(Bi[s][1], p4[1],
             fmaf(Bi[s][2], p4[2], Bi[s][3] * p4[3])));
#pragma unroll
    for (int rr = 0; rr < 32; ++rr) {
      f32x4 c4 = *(const f32x4*)&PC[buf][r0 + rr][0];
      aug[rr] = fmaf(-c4[0], y[0], fmaf(-c4[1], y[1],
                fmaf(-c4[2], y[2], fmaf(-c4[3], y[3], aug[rr]))));
    }
    if (rb == (kp >> 5)) {
      const int base = kp & 31;
#pragma unroll
      for (int s = 0; s < 4; ++s) aug[base + s] = y[s];
    }
    if (p + 1 < 32) {
      const int kn = kp + 4;
      const int nb = buf ^ 1;
      if (rb == (kn >> 5)) {
        const int nbase = kn & 31;
#pragma unroll
        for (int s = 0; s < 4; ++s) PROW[nb][s][c] = aug[nbase + s];
      }
      if (c >= kn && c < kn + 4) {
#pragma unroll
        for (int rr = 0; rr < 32; ++rr) PC[nb][r0 + rr][c - kn] = aug[rr];
      }
    }
    __syncthreads();
  }
  if (c >= D) {
#pragma unroll
    for (int rr = 0; rr < 32; ++rr) Winv[(r0 + rr) * D + (c - D)] = aug[rr];
  }
}

// ---------------------------------------------------------------------------
// Kernel 3: fp16-split MFMA Peaceman-Rachford, 64 rows/wave, asm-AGPR.
// 256 thr (4 waves), 2 colsets of 32 rows per wave, grid 256 (1 block/CU).
// accum = acc 128 + bwC 128 = 256 AGPR; arch = t 128 + temps -> no spills.
// R14: term-major MFMA issue (same-acc reuse distance 8, hides MFMA latency)
// + non-volatile MFMA asm (VALU/LDS prep overlaps MFMA execution)
// + single dependency-carrying group fence per pass.
// ---------------------------------------------------------------------------
__global__ __launch_bounds__(256, 1) void mon_main(
    const float* __restrict__ x, const float* __restrict__ Uw,
    const float* __restrict__ ub, const float* __restrict__ Wg,
    const float* __restrict__ Winvg, float* __restrict__ out) {

  __shared__ u32x4 AH[2048];   // 32 KB hi f16, [row][16 granules], XOR swizzle
  __shared__ u32x4 AL[2048];   // 32 KB lo f16

  const int tid = threadIdx.x;
  const int w = tid >> 6;
  const int l = tid & 63;
  const int l5 = l & 31;
  const int hi5 = l >> 5;
  const int rg0 = blockIdx.x * 256 + w * 64 + l5;  // colset0 row
  const int rg1 = rg0 + 32;                        // colset1 row

  const int base_g = l5 * 16 + (hi5 ^ (l5 & 7));   // swizzled A granule base
  const float* xr0 = x + (size_t)rg0 * D + hi5 * 8;
  const float* xr1 = x + (size_t)rg1 * D + hi5 * 8;

  f32x16 acc[2][4];
  f32x16 bwC[2][4];      // cC = 2*Winv*bias; AGPR-resident, MFMA-C only
  float t[2][4][16];     // signed PR state per colset (also bias / z)

  auto fence_all = [&]() {
    accs_fence(acc[0][0], acc[0][1], acc[0][2], acc[0][3],
               acc[1][0], acc[1][1], acc[1][2], acc[1][3]);
  };

  auto stageAB = [&](const float* __restrict__ M, float s) {
#pragma unroll
    for (int it = 0; it < 8; ++it) {
      const int G = tid + it * 256;
      const int i = G >> 4, g = G & 15;
      const float* src = M + i * D + g * 8;
      f32x4 a = *(const f32x4*)src;
      f32x4 b = *(const f32x4*)(src + 4);
      unsigned h0, l0_, h1, l1_, h2_, l2_, h3, l3_;
      split2(s * a[0], s * a[1], h0, l0_);
      split2(s * a[2], s * a[3], h1, l1_);
      split2(s * b[0], s * b[1], h2_, l2_);
      split2(s * b[2], s * b[3], h3, l3_);
      const int pg = g ^ (i & 7);
      AH[i * 16 + pg] = (u32x4){h0, h1, h2_, h3};
      AL[i * 16 + pg] = (u32x4){l0_, l1_, l2_, l3_};
    }
  };

  // acc[c][ft] = A_staged @ frag(t[c])^T (+ bwC if useC), term-major issue.
  auto mfma_pass = [&](bool useAbs, bool useC) {
#pragma unroll
    for (int kt = 0; kt < 8; ++kt) {
      const int jt = kt >> 1;
      const int eb = 8 * (kt & 1);
      u32x4 fH[2], fL[2];
#pragma unroll
      for (int c = 0; c < 2; ++c) {
        unsigned oh[4], ol[4];
#pragma unroll
        for (int q = 0; q < 4; ++q) {
          float a0 = t[c][jt][eb + 2 * q], a1 = t[c][jt][eb + 2 * q + 1];
          if (useAbs) { a0 = __builtin_fabsf(a0); a1 = __builtin_fabsf(a1); }
          split2(a0, a1, oh[q], ol[q]);
        }
#pragma unroll
        for (int b = 0; b < 2; ++b) {
          auto rh = __builtin_amdgcn_permlane32_swap(oh[b], oh[2 + b], false, false);
          auto rl = __builtin_amdgcn_permlane32_swap(ol[b], ol[2 + b], false, false);
          fH[c][b] = rh[0]; fH[c][2 + b] = rh[1];
          fL[c][b] = rl[0]; fL[c][2 + b] = rl[1];
        }
      }
      const int gx = base_g ^ (2 * kt);
      u32x4 ah[4], al[4];
#pragma unroll
      for (int ft = 0; ft < 4; ++ft) {
        ah[ft] = AH[ft * 512 + gx];
        al[ft] = AL[ft * 512 + gx];
      }
      // term 0: (ah, fH) -- carries init / C-in
      if (kt == 0) {
#pragma unroll
        for (int ft = 0; ft < 4; ++ft)
#pragma unroll
          for (int c = 0; c < 2; ++c) {
            if (useC) {
              mma_init(acc[c][ft], ah[ft], fH[c], bwC[c][ft]);
            } else {
              acc[c][ft] = zero16();
              mma_acc(acc[c][ft], ah[ft], fH[c]);
            }
          }
      } else {
#pragma unroll
        for (int ft = 0; ft < 4; ++ft)
#pragma unroll
          for (int c = 0; c < 2; ++c) mma_acc(acc[c][ft], ah[ft], fH[c]);
      }
      // term 1: (ah, fL)
#pragma unroll
      for (int ft = 0; ft < 4; ++ft)
#pragma unroll
        for (int c = 0; c < 2; ++c) mma_acc(acc[c][ft], ah[ft], fL[c]);
      // term 2: (al, fH)
#pragma unroll
      for (int ft = 0; ft < 4; ++ft)
#pragma unroll
        for (int c = 0; c < 2; ++c) mma_acc(acc[c][ft], al[ft], fH[c]);
    }
    fence_all();   // 24 wait states, dep-ordered vs all acc reads
  };

  // acc[c][ft] = x_rows @ A_staged^T, term-major; B-frags from global x
  auto x_pass = [&](bool useC) {
#pragma unroll
    for (int kt = 0; kt < 8; ++kt) {
      u32x4 fh[2], fl[2];
#pragma unroll
      for (int c = 0; c < 2; ++c) {
        const float* xrc = c ? xr1 : xr0;
        f32x4 xa = *(const f32x4*)(xrc + kt * 16);
        f32x4 xb = *(const f32x4*)(xrc + kt * 16 + 4);
        unsigned h0, l0_, h1, l1_, h2_, l2_, h3, l3_;
        split2(xa[0], xa[1], h0, l0_);
        split2(xa[2], xa[3], h1, l1_);
        split2(xb[0], xb[1], h2_, l2_);
        split2(xb[2], xb[3], h3, l3_);
        fh[c] = (u32x4){h0, h1, h2_, h3};
        fl[c] = (u32x4){l0_, l1_, l2_, l3_};
      }
      const int gx = base_g ^ (2 * kt);
      u32x4 ah[4], al[4];
#pragma unroll
      for (int ft = 0; ft < 4; ++ft) {
        ah[ft] = AH[ft * 512 + gx];
        al[ft] = AL[ft * 512 + gx];
      }
      if (kt == 0) {
#pragma unroll
        for (int ft = 0; ft < 4; ++ft)
#pragma unroll
          for (int c = 0; c < 2; ++c) {
            if (useC) {
              mma_init(acc[c][ft], ah[ft], fh[c], bwC[c][ft]);
            } else {
              acc[c][ft] = zero16();
              mma_acc(acc[c][ft], ah[ft], fh[c]);
            }
          }
      } else {
#pragma unroll
        for (int ft = 0; ft < 4; ++ft)
#pragma unroll
          for (int c = 0; c < 2; ++c) mma_acc(acc[c][ft], ah[ft], fh[c]);
      }
#pragma unroll
      for (int ft = 0; ft < 4; ++ft)
#pragma unroll
        for (int c = 0; c < 2; ++c) mma_acc(acc[c][ft], ah[ft], fl[c]);
#pragma unroll
      for (int ft = 0; ft < 4; ++ft)
#pragma unroll
        for (int c = 0; c < 2; ++c) mma_acc(acc[c][ft], al[ft], fh[c]);
    }
    fence_all();
  };

  // ---- Phase A: bias = x @ Uw^T + ub  (signed, into t)
  stageAB(Uw, 1.f);
  __syncthreads();
  x_pass(false);
#pragma unroll
  for (int c = 0; c < 2; ++c)
#pragma unroll
    for (int ft = 0; ft < 4; ++ft)
#pragma unroll
      for (int e2 = 0; e2 < 8; ++e2) {
        const int i0 = 32 * ft + 2 * (e2 & 1) + 8 * (e2 >> 1);
        f32x2 ubp = *(const f32x2*)(ub + i0 + 4 * hi5);
        t[c][ft][2 * e2] = acc[c][ft][2 * e2] + ubp[0];
        t[c][ft][2 * e2 + 1] = acc[c][ft][2 * e2 + 1] + ubp[1];
      }
  __syncthreads();
  stageAB(Winvg, 2.f);   // staged as 2*Winv
  __syncthreads();

  // ---- Phase A2 (= PR iter 1, u=0): acc = (2Winv)*bias = cC ; s_1 = cC
  mfma_pass(false, false);
#pragma unroll
  for (int c = 0; c < 2; ++c)
#pragma unroll
    for (int ft = 0; ft < 4; ++ft) {
      bwC[c][ft] = acc[c][ft];
#pragma unroll
      for (int e = 0; e < 16; ++e) t[c][ft][e] = acc[c][ft][e];
    }

  // ---- PR iterations 2..49 (48 full steps, no barriers)
#pragma unroll 1
  for (int it = 0; it < 48; ++it) {
    mfma_pass(true, true);   // acc = (2Winv)|s| + cC
#pragma unroll
    for (int c = 0; c < 2; ++c)
#pragma unroll
      for (int ft = 0; ft < 4; ++ft)
#pragma unroll
        for (int e = 0; e < 16; ++e)
          t[c][ft][e] = acc[c][ft][e] - __builtin_fabsf(t[c][ft][e]);
  }

  // ---- Iteration 50: z = relu(u_50) = max(acc - |s|, 0)
  mfma_pass(true, true);
#pragma unroll
  for (int c = 0; c < 2; ++c)
#pragma unroll
    for (int ft = 0; ft < 4; ++ft)
#pragma unroll
      for (int e = 0; e < 16; ++e)
        t[c][ft][e] = fmaxf(acc[c][ft][e] - __builtin_fabsf(t[c][ft][e]), 0.f);

  // ---- Phase C1: aw = z @ W^T  (W staged at scale 1; aw -> bwC)
  __syncthreads();
  stageAB(Wg, 1.f);
  __syncthreads();
  mfma_pass(false, false);
#pragma unroll
  for (int c = 0; c < 2; ++c)
#pragma unroll
    for (int ft = 0; ft < 4; ++ft) bwC[c][ft] = acc[c][ft];

  // ---- Phase C2: out = relu(x@Uw^T + aw + ub)   (aw enters as MFMA C)
  __syncthreads();
  stageAB(Uw, 1.f);
  __syncthreads();
  x_pass(true);
  float* op0 = out + (size_t)rg0 * D;
  float* op1 = out + (size_t)rg1 * D;
#pragma unroll
  for (int c = 0; c < 2; ++c) {
    float* op = c ? op1 : op0;
#pragma unroll
    for (int ft = 0; ft < 4; ++ft)
#pragma unroll
      for (int e2 = 0; e2 < 8; ++e2) {
        const int i0 = 32 * ft + 2 * (e2 & 1) + 8 * (e2 >> 1);
        f32x2 ubp = *(const f32x2*)(ub + i0 + 4 * hi5);
        float o0 = fmaxf(acc[c][ft][2 * e2] + ubp[0], 0.f);
        float o1 = fmaxf(acc[c][ft][2 * e2 + 1] + ubp[1], 0.f);
        *(f32x2*)(op + i0 + 4 * hi5) = (f32x2){o0, o1};
      }
  }
}

// ---------------------------------------------------------------------------
extern "C" void kernel_launch(void* const* d_in, const int* in_sizes, int n_in,
                              void* d_out, int out_size, void* d_ws, size_t ws_size,
                              hipStream_t stream) {
  const float* x = (const float*)d_in[0];
  const float* Uw = (const float*)d_in[1];
  const float* ub = (const float*)d_in[2];
  const float* A = (const float*)d_in[3];
  const float* B = (const float*)d_in[4];
  float* out = (float*)d_out;

  float* W = (float*)d_ws;        // 64 KB
  float* Mm = W + D * D;          // 64 KB
  float* Winv = W + 2 * D * D;    // 64 KB

  wmat_kernel<<<D, D, 0, stream>>>(A, B, W, Mm);
  inv_kernel<<<1, 1024, 0, stream>>>(Mm, Winv);

  const int batch = in_sizes[0] / D;  // 65536
  mon_main<<<batch / 256, 256, 0, stream>>>(x, Uw, ub, W, Winv, out);
}

// Round 16
// 430.823 us; speedup vs baseline: 1.5483x; 1.5483x over previous
//
#include <hip/hip_runtime.h>

#define D 128

typedef __attribute__((ext_vector_type(2))) float f32x2;
typedef __attribute__((ext_vector_type(4))) float f32x4;
typedef __attribute__((ext_vector_type(16))) float f32x16;
typedef __attribute__((ext_vector_type(2))) __fp16 fp16v2;
typedef __attribute__((ext_vector_type(4))) unsigned int u32x4;

// split f32 pair -> packed f16 hi-pair + lo-pair
__device__ __forceinline__ void split2(float a, float b, unsigned &hi, unsigned &lo) {
  fp16v2 h = __builtin_amdgcn_cvt_pkrtz(a, b);
  float ra = a - (float)h[0];
  float rb = b - (float)h[1];
  fp16v2 lv = __builtin_amdgcn_cvt_pkrtz(ra, rb);
  hi = __builtin_bit_cast(unsigned, h);
  lo = __builtin_bit_cast(unsigned, lv);
}

// Inline-asm MFMA, AGPR-forced, VOLATILE (R15 lesson: non-volatile lets the
// scheduler hoist LDS/VALU across the whole pass -> live-range blowup ->
// spills return. Volatile pins program order; we fix MFMA latency by ISSUE
// ORDER instead: term-major sweeps give same-acc reuse distance 8).
// Leading s_nop 1 covers VALU-write -> MFMA-read (R13-proven).
__device__ __forceinline__ void mma_acc(f32x16 &c, u32x4 a, u32x4 b) {
  asm volatile("s_nop 1\n\tv_mfma_f32_32x32x16_f16 %0, %1, %2, %0"
               : "+a"(c) : "v"(a), "v"(b));
}
__device__ __forceinline__ void mma_init(f32x16 &d, u32x4 a, u32x4 b,
                                         const f32x16 &cin) {
  asm volatile("s_nop 1\n\tv_mfma_f32_32x32x16_f16 %0, %1, %2, %3"
               : "=&a"(d) : "v"(a), "v"(b), "a"(cin));
}
__device__ __forceinline__ void mfma_fence() {
  asm volatile("s_nop 7\n\ts_nop 7\n\ts_nop 7");
}

__device__ __forceinline__ f32x16 zero16() {
  f32x16 z;
#pragma unroll
  for (int e = 0; e < 16; ++e) z[e] = 0.f;
  return z;
}

// ---------------------------------------------------------------------------
// Kernel 1: W = 0.95 I - A^T A + B - B^T ;  Mm = 2 I - W
// ---------------------------------------------------------------------------
__global__ void wmat_kernel(const float* __restrict__ A, const float* __restrict__ B,
                            float* __restrict__ W, float* __restrict__ Mm) {
  const int i = blockIdx.x;
  const int j = threadIdx.x;
  float s = 0.f;
#pragma unroll 8
  for (int k = 0; k < D; ++k) s = fmaf(A[k * D + i], A[k * D + j], s);
  const float diag = (i == j) ? 1.f : 0.f;
  const float w = 0.95f * diag - s + B[i * D + j] - B[j * D + i];
  W[i * D + j] = w;
  Mm[i * D + j] = 2.f * diag - w;
}

// ---------------------------------------------------------------------------
// Kernel 2: Winv = Mm^{-1}, rank-4 block Gauss-Jordan, 32 barriers.
// ---------------------------------------------------------------------------
__global__ __launch_bounds__(1024) void inv_kernel(const float* __restrict__ Mm,
                                                   float* __restrict__ Winv) {
  __shared__ float PROW[2][4][256];
  __shared__ __align__(16) float PC[2][D][4];
  const int t = threadIdx.x;
  const int c = t & 255;
  const int rb = t >> 8;
  const int r0 = rb * 32;
  float aug[32];
#pragma unroll
  for (int rr = 0; rr < 32; ++rr) {
    const int r = r0 + rr;
    aug[rr] = (c < D) ? Mm[r * D + c] : ((c - D == r) ? 1.f : 0.f);
  }
  if (rb == 0) {
#pragma unroll
    for (int s = 0; s < 4; ++s) PROW[0][s][c] = aug[s];
  }
  if (c < 4) {
#pragma unroll
    for (int rr = 0; rr < 32; ++rr) PC[0][r0 + rr][c] = aug[rr];
  }
  __syncthreads();
#pragma unroll
  for (int p = 0; p < 32; ++p) {
    const int buf = p & 1;
    const int kp = 4 * p;
    float p4[4], Bk[4][4], Bi[4][4];
#pragma unroll
    for (int s = 0; s < 4; ++s) p4[s] = PROW[buf][s][c];
#pragma unroll
    for (int s = 0; s < 4; ++s)
#pragma unroll
      for (int j = 0; j < 4; ++j) {
        Bk[s][j] = PROW[buf][s][kp + j];
        Bi[s][j] = (s == j) ? 1.f : 0.f;
      }
#pragma unroll
    for (int k = 0; k < 4; ++k) {
      const float ip = 1.f / Bk[k][k];
#pragma unroll
      for (int j = 0; j < 4; ++j) { Bk[k][j] *= ip; Bi[k][j] *= ip; }
#pragma unroll
      for (int s = 0; s < 4; ++s)
        if (s != k) {
          const float f = Bk[s][k];
#pragma unroll
          for (int j = 0; j < 4; ++j) {
            Bk[s][j] = fmaf(-f, Bk[k][j], Bk[s][j]);
            Bi[s][j] = fmaf(-f, Bi[k][j], Bi[s][j]);
          }
        }
    }
    float y[4];
#pragma unroll
    for (int s = 0; s < 4; ++s)
      y[s] = fmaf(Bi[s][0], p4[0], fmaf(Bi[s][1], p4[1],
             fmaf(Bi[s][2], p4[2], Bi[s][3] * p4[3])));
#pragma unroll
    for (int rr = 0; rr < 32; ++rr) {
      f32x4 c4 = *(const f32x4*)&PC[buf][r0 + rr][0];
      aug[rr] = fmaf(-c4[0], y[0], fmaf(-c4[1], y[1],
                fmaf(-c4[2], y[2], fmaf(-c4[3], y[3], aug[rr]))));
    }
    if (rb == (kp >> 5)) {
      const int base = kp & 31;
#pragma unroll
      for (int s = 0; s < 4; ++s) aug[base + s] = y[s];
    }
    if (p + 1 < 32) {
      const int kn = kp + 4;
      const int nb = buf ^ 1;
      if (rb == (kn >> 5)) {
        const int nbase = kn & 31;
#pragma unroll
        for (int s = 0; s < 4; ++s) PROW[nb][s][c] = aug[nbase + s];
      }
      if (c >= kn && c < kn + 4) {
#pragma unroll
        for (int rr = 0; rr < 32; ++rr) PC[nb][r0 + rr][c - kn] = aug[rr];
      }
    }
    __syncthreads();
  }
  if (c >= D) {
#pragma unroll
    for (int rr = 0; rr < 32; ++rr) Winv[(r0 + rr) * D + (c - D)] = aug[rr];
  }
}

// ---------------------------------------------------------------------------
// Kernel 3: fp16-split MFMA Peaceman-Rachford, 64 rows/wave, asm-AGPR.
// 256 thr (4 waves), 2 colsets of 32 rows per wave, grid 256 (1 block/CU).
// accum = acc 128 + bwC 128 = 256 AGPR; arch = t 128 + temps -> no spills.
// R16 = R13 (volatile, spill-free, correct) + TERM-MAJOR issue order:
// per kt load ah[4]/al[4] once, then 3 sweeps of 8 MFMAs over (ft,c) ->
// same-acc reuse distance 8 (~64 cyc) hides MFMA latency that made R13
// average ~80 cyc/MFMA on distance-1 chains.
// ---------------------------------------------------------------------------
__global__ __launch_bounds__(256, 1) void mon_main(
    const float* __restrict__ x, const float* __restrict__ Uw,
    const float* __restrict__ ub, const float* __restrict__ Wg,
    const float* __restrict__ Winvg, float* __restrict__ out) {

  __shared__ u32x4 AH[2048];   // 32 KB hi f16, [row][16 granules], XOR swizzle
  __shared__ u32x4 AL[2048];   // 32 KB lo f16

  const int tid = threadIdx.x;
  const int w = tid >> 6;
  const int l = tid & 63;
  const int l5 = l & 31;
  const int hi5 = l >> 5;
  const int rg0 = blockIdx.x * 256 + w * 64 + l5;  // colset0 row
  const int rg1 = rg0 + 32;                        // colset1 row

  const int base_g = l5 * 16 + (hi5 ^ (l5 & 7));   // swizzled A granule base
  const float* xr0 = x + (size_t)rg0 * D + hi5 * 8;
  const float* xr1 = x + (size_t)rg1 * D + hi5 * 8;

  f32x16 acc[2][4];
  f32x16 bwC[2][4];      // cC = 2*Winv*bias; AGPR-resident, MFMA-C only
  float t[2][4][16];     // signed PR state per colset (also bias / z)

  auto stageAB = [&](const float* __restrict__ M, float s) {
#pragma unroll
    for (int it = 0; it < 8; ++it) {
      const int G = tid + it * 256;
      const int i = G >> 4, g = G & 15;
      const float* src = M + i * D + g * 8;
      f32x4 a = *(const f32x4*)src;
      f32x4 b = *(const f32x4*)(src + 4);
      unsigned h0, l0_, h1, l1_, h2_, l2_, h3, l3_;
      split2(s * a[0], s * a[1], h0, l0_);
      split2(s * a[2], s * a[3], h1, l1_);
      split2(s * b[0], s * b[1], h2_, l2_);
      split2(s * b[2], s * b[3], h3, l3_);
      const int pg = g ^ (i & 7);
      AH[i * 16 + pg] = (u32x4){h0, h1, h2_, h3};
      AL[i * 16 + pg] = (u32x4){l0_, l1_, l2_, l3_};
    }
  };

  // Issue the 24 MFMAs of one kt-group term-major over (ft, c):
  // term0 (ah,fH) carries init/C-in; term1 (ah,fL); term2 (al,fH).
  auto issue_kt = [&](const u32x4 (&ah)[4], const u32x4 (&al)[4],
                      const u32x4 (&fH)[2], const u32x4 (&fL)[2],
                      bool first, bool useC) {
    if (first) {
#pragma unroll
      for (int ft = 0; ft < 4; ++ft)
#pragma unroll
        for (int c = 0; c < 2; ++c) {
          if (useC) {
            mma_init(acc[c][ft], ah[ft], fH[c], bwC[c][ft]);
          } else {
            acc[c][ft] = zero16();
            mma_acc(acc[c][ft], ah[ft], fH[c]);
          }
        }
    } else {
#pragma unroll
      for (int ft = 0; ft < 4; ++ft)
#pragma unroll
        for (int c = 0; c < 2; ++c) mma_acc(acc[c][ft], ah[ft], fH[c]);
    }
#pragma unroll
    for (int ft = 0; ft < 4; ++ft)
#pragma unroll
      for (int c = 0; c < 2; ++c) mma_acc(acc[c][ft], ah[ft], fL[c]);
#pragma unroll
    for (int ft = 0; ft < 4; ++ft)
#pragma unroll
      for (int c = 0; c < 2; ++c) mma_acc(acc[c][ft], al[ft], fH[c]);
  };

  // acc[c][ft] = A_staged @ frag(t[c])^T (+ bwC if useC)
  auto mfma_pass = [&](bool useAbs, bool useC) {
#pragma unroll
    for (int kt = 0; kt < 8; ++kt) {
      const int jt = kt >> 1;
      const int eb = 8 * (kt & 1);
      u32x4 fH[2], fL[2];
#pragma unroll
      for (int c = 0; c < 2; ++c) {
        unsigned oh[4], ol[4];
#pragma unroll
        for (int q = 0; q < 4; ++q) {
          float a0 = t[c][jt][eb + 2 * q], a1 = t[c][jt][eb + 2 * q + 1];
          if (useAbs) { a0 = __builtin_fabsf(a0); a1 = __builtin_fabsf(a1); }
          split2(a0, a1, oh[q], ol[q]);
        }
#pragma unroll
        for (int b = 0; b < 2; ++b) {
          auto rh = __builtin_amdgcn_permlane32_swap(oh[b], oh[2 + b], false, false);
          auto rl = __builtin_amdgcn_permlane32_swap(ol[b], ol[2 + b], false, false);
          fH[c][b] = rh[0]; fH[c][2 + b] = rh[1];
          fL[c][b] = rl[0]; fL[c][2 + b] = rl[1];
        }
      }
      const int gx = base_g ^ (2 * kt);
      u32x4 ah[4], al[4];
#pragma unroll
      for (int ft = 0; ft < 4; ++ft) {
        ah[ft] = AH[ft * 512 + gx];
        al[ft] = AL[ft * 512 + gx];
      }
      issue_kt(ah, al, fH, fL, kt == 0, useC);
    }
    mfma_fence();   // MFMA-write -> VALU-read hazard barrier
  };

  // acc[c][ft] = x_rows @ A_staged^T ; B-frags straight from global x
  auto x_pass = [&](bool useC) {
#pragma unroll
    for (int kt = 0; kt < 8; ++kt) {
      u32x4 fh[2], fl[2];
#pragma unroll
      for (int c = 0; c < 2; ++c) {
        const float* xrc = c ? xr1 : xr0;
        f32x4 xa = *(const f32x4*)(xrc + kt * 16);
        f32x4 xb = *(const f32x4*)(xrc + kt * 16 + 4);
        unsigned h0, l0_, h1, l1_, h2_, l2_, h3, l3_;
        split2(xa[0], xa[1], h0, l0_);
        split2(xa[2], xa[3], h1, l1_);
        split2(xb[0], xb[1], h2_, l2_);
        split2(xb[2], xb[3], h3, l3_);
        fh[c] = (u32x4){h0, h1, h2_, h3};
        fl[c] = (u32x4){l0_, l1_, l2_, l3_};
      }
      const int gx = base_g ^ (2 * kt);
      u32x4 ah[4], al[4];
#pragma unroll
      for (int ft = 0; ft < 4; ++ft) {
        ah[ft] = AH[ft * 512 + gx];
        al[ft] = AL[ft * 512 + gx];
      }
      issue_kt(ah, al, fh, fl, kt == 0, useC);
    }
    mfma_fence();
  };

  // ---- Phase A: bias = x @ Uw^T + ub  (signed, into t)
  stageAB(Uw, 1.f);
  __syncthreads();
  x_pass(false);
#pragma unroll
  for (int c = 0; c < 2; ++c)
#pragma unroll
    for (int ft = 0; ft < 4; ++ft)
#pragma unroll
      for (int e2 = 0; e2 < 8; ++e2) {
        const int i0 = 32 * ft + 2 * (e2 & 1) + 8 * (e2 >> 1);
        f32x2 ubp = *(const f32x2*)(ub + i0 + 4 * hi5);
        t[c][ft][2 * e2] = acc[c][ft][2 * e2] + ubp[0];
        t[c][ft][2 * e2 + 1] = acc[c][ft][2 * e2 + 1] + ubp[1];
      }
  __syncthreads();
  stageAB(Winvg, 2.f);   // staged as 2*Winv
  __syncthreads();

  // ---- Phase A2 (= PR iter 1, u=0): acc = (2Winv)*bias = cC ; s_1 = cC
  mfma_pass(false, false);
#pragma unroll
  for (int c = 0; c < 2; ++c)
#pragma unroll
    for (int ft = 0; ft < 4; ++ft) {
      bwC[c][ft] = acc[c][ft];
#pragma unroll
      for (int e = 0; e < 16; ++e) t[c][ft][e] = acc[c][ft][e];
    }

  // ---- PR iterations 2..49 (48 full steps, no barriers)
#pragma unroll 1
  for (int it = 0; it < 48; ++it) {
    mfma_pass(true, true);   // acc = (2Winv)|s| + cC
#pragma unroll
    for (int c = 0; c < 2; ++c)
#pragma unroll
      for (int ft = 0; ft < 4; ++ft)
#pragma unroll
        for (int e = 0; e < 16; ++e)
          t[c][ft][e] = acc[c][ft][e] - __builtin_fabsf(t[c][ft][e]);
  }

  // ---- Iteration 50: z = relu(u_50) = max(acc - |s|, 0)
  mfma_pass(true, true);
#pragma unroll
  for (int c = 0; c < 2; ++c)
#pragma unroll
    for (int ft = 0; ft < 4; ++ft)
#pragma unroll
      for (int e = 0; e < 16; ++e)
        t[c][ft][e] = fmaxf(acc[c][ft][e] - __builtin_fabsf(t[c][ft][e]), 0.f);

  // ---- Phase C1: aw = z @ W^T  (W staged at scale 1; aw -> bwC)
  __syncthreads();
  stageAB(Wg, 1.f);
  __syncthreads();
  mfma_pass(false, false);
#pragma unroll
  for (int c = 0; c < 2; ++c)
#pragma unroll
    for (int ft = 0; ft < 4; ++ft) bwC[c][ft] = acc[c][ft];

  // ---- Phase C2: out = relu(x@Uw^T + aw + ub)   (aw enters as MFMA C)
  __syncthreads();
  stageAB(Uw, 1.f);
  __syncthreads();
  x_pass(true);
  float* op0 = out + (size_t)rg0 * D;
  float* op1 = out + (size_t)rg1 * D;
#pragma unroll
  for (int c = 0; c < 2; ++c) {
    float* op = c ? op1 : op0;
#pragma unroll
    for (int ft = 0; ft < 4; ++ft)
#pragma unroll
      for (int e2 = 0; e2 < 8; ++e2) {
        const int i0 = 32 * ft + 2 * (e2 & 1) + 8 * (e2 >> 1);
        f32x2 ubp = *(const f32x2*)(ub + i0 + 4 * hi5);
        float o0 = fmaxf(acc[c][ft][2 * e2] + ubp[0], 0.f);
        float o1 = fmaxf(acc[c][ft][2 * e2 + 1] + ubp[1], 0.f);
        *(f32x2*)(op + i0 + 4 * hi5) = (f32x2){o0, o1};
      }
  }
}

// ---------------------------------------------------------------------------
extern "C" void kernel_launch(void* const* d_in, const int* in_sizes, int n_in,
                              void* d_out, int out_size, void* d_ws, size_t ws_size,
                              hipStream_t stream) {
  const float* x = (const float*)d_in[0];
  const float* Uw = (const float*)d_in[1];
  const float* ub = (const float*)d_in[2];
  const float* A = (const float*)d_in[3];
  const float* B = (const float*)d_in[4];
  float* out = (float*)d_out;

  float* W = (float*)d_ws;        // 64 KB
  float* Mm = W + D * D;          // 64 KB
  float* Winv = W + 2 * D * D;    // 64 KB

  wmat_kernel<<<D, D, 0, stream>>>(A, B, W, Mm);
  inv_kernel<<<1, 1024, 0, stream>>>(Mm, Winv);

  const int batch = in_sizes[0] / D;  // 65536
  mon_main<<<batch / 256, 256, 0, stream>>>(x, Uw, ub, W, Winv, out);
}

// Round 17
// 401.627 us; speedup vs baseline: 1.6608x; 1.0727x over previous
//
#include <hip/hip_runtime.h>

#define D 128

typedef __attribute__((ext_vector_type(2))) float f32x2;
typedef __attribute__((ext_vector_type(4))) float f32x4;
typedef __attribute__((ext_vector_type(16))) float f32x16;
typedef __attribute__((ext_vector_type(2))) __fp16 fp16v2;
typedef __attribute__((ext_vector_type(4))) unsigned int u32x4;

// split f32 pair -> packed f16 hi-pair + lo-pair
__device__ __forceinline__ void split2(float a, float b, unsigned &hi, unsigned &lo) {
  fp16v2 h = __builtin_amdgcn_cvt_pkrtz(a, b);
  float ra = a - (float)h[0];
  float rb = b - (float)h[1];
  fp16v2 lv = __builtin_amdgcn_cvt_pkrtz(ra, rb);
  hi = __builtin_bit_cast(unsigned, h);
  lo = __builtin_bit_cast(unsigned, lv);
}

// Inline-asm MFMA, AGPR-forced, volatile (R13-proven correct + spill-free;
// R15 showed non-volatile causes live-range blowup -> spills; R16 showed
// issue order is irrelevant: same-acc chains are HW-forwarded at full rate).
// Leading s_nop 1 covers VALU-write -> MFMA-read hazards.
__device__ __forceinline__ void mma_acc(f32x16 &c, u32x4 a, u32x4 b) {
  asm volatile("s_nop 1\n\tv_mfma_f32_32x32x16_f16 %0, %1, %2, %0"
               : "+a"(c) : "v"(a), "v"(b));
}
__device__ __forceinline__ void mma_init(f32x16 &d, u32x4 a, u32x4 b,
                                         const f32x16 &cin) {
  asm volatile("s_nop 1\n\tv_mfma_f32_32x32x16_f16 %0, %1, %2, %3"
               : "=&a"(d) : "v"(a), "v"(b), "a"(cin));
}
__device__ __forceinline__ void mfma_fence() {
  asm volatile("s_nop 7\n\ts_nop 7\n\ts_nop 7");
}

__device__ __forceinline__ f32x16 zero16() {
  f32x16 z;
#pragma unroll
  for (int e = 0; e < 16; ++e) z[e] = 0.f;
  return z;
}

// ---------------------------------------------------------------------------
// Kernel 1: W = 0.95 I - A^T A + B - B^T ;  Mm = 2 I - W
// ---------------------------------------------------------------------------
__global__ void wmat_kernel(const float* __restrict__ A, const float* __restrict__ B,
                            float* __restrict__ W, float* __restrict__ Mm) {
  const int i = blockIdx.x;
  const int j = threadIdx.x;
  float s = 0.f;
#pragma unroll 8
  for (int k = 0; k < D; ++k) s = fmaf(A[k * D + i], A[k * D + j], s);
  const float diag = (i == j) ? 1.f : 0.f;
  const float w = 0.95f * diag - s + B[i * D + j] - B[j * D + i];
  W[i * D + j] = w;
  Mm[i * D + j] = 2.f * diag - w;
}

// ---------------------------------------------------------------------------
// Kernel 2: Winv = Mm^{-1}, rank-4 block Gauss-Jordan, 32 barriers.
// ---------------------------------------------------------------------------
__global__ __launch_bounds__(1024) void inv_kernel(const float* __restrict__ Mm,
                                                   float* __restrict__ Winv) {
  __shared__ float PROW[2][4][256];
  __shared__ __align__(16) float PC[2][D][4];
  const int t = threadIdx.x;
  const int c = t & 255;
  const int rb = t >> 8;
  const int r0 = rb * 32;
  float aug[32];
#pragma unroll
  for (int rr = 0; rr < 32; ++rr) {
    const int r = r0 + rr;
    aug[rr] = (c < D) ? Mm[r * D + c] : ((c - D == r) ? 1.f : 0.f);
  }
  if (rb == 0) {
#pragma unroll
    for (int s = 0; s < 4; ++s) PROW[0][s][c] = aug[s];
  }
  if (c < 4) {
#pragma unroll
    for (int rr = 0; rr < 32; ++rr) PC[0][r0 + rr][c] = aug[rr];
  }
  __syncthreads();
#pragma unroll
  for (int p = 0; p < 32; ++p) {
    const int buf = p & 1;
    const int kp = 4 * p;
    float p4[4], Bk[4][4], Bi[4][4];
#pragma unroll
    for (int s = 0; s < 4; ++s) p4[s] = PROW[buf][s][c];
#pragma unroll
    for (int s = 0; s < 4; ++s)
#pragma unroll
      for (int j = 0; j < 4; ++j) {
        Bk[s][j] = PROW[buf][s][kp + j];
        Bi[s][j] = (s == j) ? 1.f : 0.f;
      }
#pragma unroll
    for (int k = 0; k < 4; ++k) {
      const float ip = 1.f / Bk[k][k];
#pragma unroll
      for (int j = 0; j < 4; ++j) { Bk[k][j] *= ip; Bi[k][j] *= ip; }
#pragma unroll
      for (int s = 0; s < 4; ++s)
        if (s != k) {
          const float f = Bk[s][k];
#pragma unroll
          for (int j = 0; j < 4; ++j) {
            Bk[s][j] = fmaf(-f, Bk[k][j], Bk[s][j]);
            Bi[s][j] = fmaf(-f, Bi[k][j], Bi[s][j]);
          }
        }
    }
    float y[4];
#pragma unroll
    for (int s = 0; s < 4; ++s)
      y[s] = fmaf(Bi[s][0], p4[0], fmaf(Bi[s][1], p4[1],
             fmaf(Bi[s][2], p4[2], Bi[s][3] * p4[3])));
#pragma unroll
    for (int rr = 0; rr < 32; ++rr) {
      f32x4 c4 = *(const f32x4*)&PC[buf][r0 + rr][0];
      aug[rr] = fmaf(-c4[0], y[0], fmaf(-c4[1], y[1],
                fmaf(-c4[2], y[2], fmaf(-c4[3], y[3], aug[rr]))));
    }
    if (rb == (kp >> 5)) {
      const int base = kp & 31;
#pragma unroll
      for (int s = 0; s < 4; ++s) aug[base + s] = y[s];
    }
    if (p + 1 < 32) {
      const int kn = kp + 4;
      const int nb = buf ^ 1;
      if (rb == (kn >> 5)) {
        const int nbase = kn & 31;
#pragma unroll
        for (int s = 0; s < 4; ++s) PROW[nb][s][c] = aug[nbase + s];
      }
      if (c >= kn && c < kn + 4) {
#pragma unroll
        for (int rr = 0; rr < 32; ++rr) PC[nb][r0 + rr][c - kn] = aug[rr];
      }
    }
    __syncthreads();
  }
  if (c >= D) {
#pragma unroll
    for (int rr = 0; rr < 32; ++rr) Winv[(r0 + rr) * D + (c - D)] = aug[rr];
  }
}

// ---------------------------------------------------------------------------
// Kernel 3: fp16-split MFMA Peaceman-Rachford, 32 rows/wave, 2 waves/SIMD.
// 256 thr (4 waves), grid 512 (2 blocks/CU), __launch_bounds__(256, 2):
// R11 measured (256,2) -> 128 arch-VGPR cap + 2 waves/SIMD resident.
// This config's arch demand FITS the cap: t 64 + frags 16 + ah/al 8 +
// addr ~25 = ~115 <= 128. accum (asm-forced AGPR) = acc 64 + bwC 64 = 128.
// Total 256/wave x 2 waves = 512-reg pool. Wave B's VALU/LDS prep now hides
// under wave A's MFMA occupancy (R16 showed 1 wave/SIMD = serial sum:
// 192 MFMA x 32cyc + VALU + LDS waits; co-residency overlaps them).
// State s = u: s_next = (2Winv)|s| + cC - |s|; cC via MFMA C-operand.
// ---------------------------------------------------------------------------
__global__ __launch_bounds__(256, 2) void mon_main(
    const float* __restrict__ x, const float* __restrict__ Uw,
    const float* __restrict__ ub, const float* __restrict__ Wg,
    const float* __restrict__ Winvg, float* __restrict__ out) {

  __shared__ u32x4 AH[2048];   // 32 KB hi f16, [row][16 granules], XOR swizzle
  __shared__ u32x4 AL[2048];   // 32 KB lo f16

  const int tid = threadIdx.x;
  const int w = tid >> 6;
  const int l = tid & 63;
  const int l5 = l & 31;
  const int hi5 = l >> 5;
  const int rg = blockIdx.x * 128 + w * 32 + l5;   // this lane's batch row

  const int base_g = l5 * 16 + (hi5 ^ (l5 & 7));   // swizzled A granule base
  const float* xr = x + (size_t)rg * D + hi5 * 8;

  f32x16 acc[4];     // AGPR (asm-forced)
  f32x16 bwC[4];     // cC = 2*Winv*bias; AGPR, MFMA-C only
  float t[4][16];    // signed PR state s = u (also bias / z)

  auto stageAB = [&](const float* __restrict__ M, float s) {
#pragma unroll
    for (int it = 0; it < 8; ++it) {
      const int G = tid + it * 256;
      const int i = G >> 4, g = G & 15;
      const float* src = M + i * D + g * 8;
      f32x4 a = *(const f32x4*)src;
      f32x4 b = *(const f32x4*)(src + 4);
      unsigned h0, l0_, h1, l1_, h2_, l2_, h3, l3_;
      split2(s * a[0], s * a[1], h0, l0_);
      split2(s * a[2], s * a[3], h1, l1_);
      split2(s * b[0], s * b[1], h2_, l2_);
      split2(s * b[2], s * b[3], h3, l3_);
      const int pg = g ^ (i & 7);
      AH[i * 16 + pg] = (u32x4){h0, h1, h2_, h3};
      AL[i * 16 + pg] = (u32x4){l0_, l1_, l2_, l3_};
    }
  };

  // acc[ft] = A_staged @ frag(t)^T (+ bwC if useC); useAbs -> frags from |t|
  auto mfma_pass = [&](bool useAbs, bool useC) {
#pragma unroll
    for (int kt = 0; kt < 8; ++kt) {
      const int jt = kt >> 1;
      const int eb = 8 * (kt & 1);
      unsigned oh[4], ol[4];
#pragma unroll
      for (int q = 0; q < 4; ++q) {
        float a0 = t[jt][eb + 2 * q], a1 = t[jt][eb + 2 * q + 1];
        if (useAbs) { a0 = __builtin_fabsf(a0); a1 = __builtin_fabsf(a1); }
        split2(a0, a1, oh[q], ol[q]);
      }
      u32x4 fH, fL;
#pragma unroll
      for (int b = 0; b < 2; ++b) {
        auto rh = __builtin_amdgcn_permlane32_swap(oh[b], oh[2 + b], false, false);
        auto rl = __builtin_amdgcn_permlane32_swap(ol[b], ol[2 + b], false, false);
        fH[b] = rh[0]; fH[2 + b] = rh[1];
        fL[b] = rl[0]; fL[2 + b] = rl[1];
      }
      const int gx = base_g ^ (2 * kt);
#pragma unroll
      for (int ft = 0; ft < 4; ++ft) {
        const u32x4 ah = AH[ft * 512 + gx];
        const u32x4 al = AL[ft * 512 + gx];
        if (kt == 0) {
          if (useC) {
            mma_init(acc[ft], ah, fH, bwC[ft]);
          } else {
            acc[ft] = zero16();
            mma_acc(acc[ft], ah, fH);
          }
        } else {
          mma_acc(acc[ft], ah, fH);
        }
        mma_acc(acc[ft], ah, fL);
        mma_acc(acc[ft], al, fH);
      }
    }
    mfma_fence();   // MFMA-write -> VALU-read hazard barrier
  };

  // acc[ft] = x_row @ A_staged^T ; B-frags straight from global x
  auto x_pass = [&](bool useC) {
#pragma unroll
    for (int kt = 0; kt < 8; ++kt) {
      f32x4 xa = *(const f32x4*)(xr + kt * 16);
      f32x4 xb = *(const f32x4*)(xr + kt * 16 + 4);
      unsigned h0, l0_, h1, l1_, h2_, l2_, h3, l3_;
      split2(xa[0], xa[1], h0, l0_);
      split2(xa[2], xa[3], h1, l1_);
      split2(xb[0], xb[1], h2_, l2_);
      split2(xb[2], xb[3], h3, l3_);
      u32x4 fh = (u32x4){h0, h1, h2_, h3};
      u32x4 fl = (u32x4){l0_, l1_, l2_, l3_};
      const int gx = base_g ^ (2 * kt);
#pragma unroll
      for (int ft = 0; ft < 4; ++ft) {
        const u32x4 ah = AH[ft * 512 + gx];
        const u32x4 al = AL[ft * 512 + gx];
        if (kt == 0) {
          if (useC) {
            mma_init(acc[ft], ah, fh, bwC[ft]);
          } else {
            acc[ft] = zero16();
            mma_acc(acc[ft], ah, fh);
          }
        } else {
          mma_acc(acc[ft], ah, fh);
        }
        mma_acc(acc[ft], ah, fl);
        mma_acc(acc[ft], al, fh);
      }
    }
    mfma_fence();
  };

  // ---- Phase A: bias = x @ Uw^T + ub  (signed, into t)
  stageAB(Uw, 1.f);
  __syncthreads();
  x_pass(false);
#pragma unroll
  for (int ft = 0; ft < 4; ++ft)
#pragma unroll
    for (int e2 = 0; e2 < 8; ++e2) {
      const int i0 = 32 * ft + 2 * (e2 & 1) + 8 * (e2 >> 1);
      f32x2 ubp = *(const f32x2*)(ub + i0 + 4 * hi5);
      t[ft][2 * e2] = acc[ft][2 * e2] + ubp[0];
      t[ft][2 * e2 + 1] = acc[ft][2 * e2 + 1] + ubp[1];
    }
  __syncthreads();
  stageAB(Winvg, 2.f);   // staged as 2*Winv
  __syncthreads();

  // ---- Phase A2 (= PR iter 1, u=0): acc = (2Winv)*bias = cC ; s_1 = cC
  mfma_pass(false, false);
#pragma unroll
  for (int ft = 0; ft < 4; ++ft) {
    bwC[ft] = acc[ft];
#pragma unroll
    for (int e = 0; e < 16; ++e) t[ft][e] = acc[ft][e];
  }

  // ---- PR iterations 2..49 (48 full steps, no barriers)
#pragma unroll 1
  for (int it = 0; it < 48; ++it) {
    mfma_pass(true, true);   // acc = (2Winv)|s| + cC
#pragma unroll
    for (int ft = 0; ft < 4; ++ft)
#pragma unroll
      for (int e = 0; e < 16; ++e)
        t[ft][e] = acc[ft][e] - __builtin_fabsf(t[ft][e]);
  }

  // ---- Iteration 50: z = relu(u_50) = max(acc - |s|, 0)
  mfma_pass(true, true);
#pragma unroll
  for (int ft = 0; ft < 4; ++ft)
#pragma unroll
    for (int e = 0; e < 16; ++e)
      t[ft][e] = fmaxf(acc[ft][e] - __builtin_fabsf(t[ft][e]), 0.f);

  // ---- Phase C1: aw = z @ W^T  (W staged at scale 1; aw -> bwC)
  __syncthreads();
  stageAB(Wg, 1.f);
  __syncthreads();
  mfma_pass(false, false);
#pragma unroll
  for (int ft = 0; ft < 4; ++ft) bwC[ft] = acc[ft];

  // ---- Phase C2: out = relu(x@Uw^T + aw + ub)   (aw enters as MFMA C)
  __syncthreads();
  stageAB(Uw, 1.f);
  __syncthreads();
  x_pass(true);
  float* op = out + (size_t)rg * D;
#pragma unroll
  for (int ft = 0; ft < 4; ++ft)
#pragma unroll
    for (int e2 = 0; e2 < 8; ++e2) {
      const int i0 = 32 * ft + 2 * (e2 & 1) + 8 * (e2 >> 1);
      f32x2 ubp = *(const f32x2*)(ub + i0 + 4 * hi5);
      float o0 = fmaxf(acc[ft][2 * e2] + ubp[0], 0.f);
      float o1 = fmaxf(acc[ft][2 * e2 + 1] + ubp[1], 0.f);
      *(f32x2*)(op + i0 + 4 * hi5) = (f32x2){o0, o1};
    }
}

// ---------------------------------------------------------------------------
extern "C" void kernel_launch(void* const* d_in, const int* in_sizes, int n_in,
                              void* d_out, int out_size, void* d_ws, size_t ws_size,
                              hipStream_t stream) {
  const float* x = (const float*)d_in[0];
  const float* Uw = (const float*)d_in[1];
  const float* ub = (const float*)d_in[2];
  const float* A = (const float*)d_in[3];
  const float* B = (const float*)d_in[4];
  float* out = (float*)d_out;

  float* W = (float*)d_ws;        // 64 KB
  float* Mm = W + D * D;          // 64 KB
  float* Winv = W + 2 * D * D;    // 64 KB

  wmat_kernel<<<D, D, 0, stream>>>(A, B, W, Mm);
  inv_kernel<<<1, 1024, 0, stream>>>(Mm, Winv);

  const int batch = in_sizes[0] / D;  // 65536
  mon_main<<<batch / 128, 256, 0, stream>>>(x, Uw, ub, W, Winv, out);
}